// Round 9
// baseline (177.523 us; speedup 1.0000x reference)
//
#include <hip/hip_runtime.h>
#include <math.h>

#define NSEQ   4096
#define DMODEL 640
#define NHEAD  8
#define DHEAD  64
#define INNER  512   // NHEAD*DHEAD
#define KVSPLIT 2

typedef _Float16 f16;
typedef _Float16 f16x8 __attribute__((ext_vector_type(8)));
typedef _Float16 f16x4 __attribute__((ext_vector_type(4)));
typedef float    f32x4 __attribute__((ext_vector_type(4)));

#define MFMA16(a, b, c) __builtin_amdgcn_mfma_f32_16x16x32_f16((a), (b), (c), 0, 0, 0)

// softmax scale 1/8 folded with log2(e): softmax runs in exp2 domain
#define QSCALE 0.18033688011112042f

// global -> LDS direct copy, 16B/lane, wave-uniform LDS base.
__device__ __forceinline__ void gl16(const f16* g, f16* l) {
    __builtin_amdgcn_global_load_lds(
        (const __attribute__((address_space(1))) unsigned int*)g,
        (__attribute__((address_space(3))) unsigned int*)l, 16, 0, 0);
}

// ---------------------------------------------------------------------------
// Prep: x (f32) -> xh (f16), 8 elems/thread
// ---------------------------------------------------------------------------
__global__ __launch_bounds__(256) void cvt_x(const float* __restrict__ x,
                                             f16* __restrict__ xh) {
    int i = (blockIdx.x * 256 + threadIdx.x) * 8;
    float4 a = *(const float4*)&x[i];
    float4 b = *(const float4*)&x[i + 4];
    f16x8 o = {(f16)a.x, (f16)a.y, (f16)a.z, (f16)a.w,
               (f16)b.x, (f16)b.y, (f16)b.z, (f16)b.w};
    *(f16x8*)&xh[i] = o;
}

// ---------------------------------------------------------------------------
// Prep: transpose+convert Wq/Wk/Wv f32 [640][512] -> f16 [512][640]
// ---------------------------------------------------------------------------
__global__ __launch_bounds__(256) void transpose_cvt3(
    const float* __restrict__ Wq, const float* __restrict__ Wk,
    const float* __restrict__ Wv,
    f16* __restrict__ WTq, f16* __restrict__ WTk, f16* __restrict__ WTv) {
    __shared__ __align__(16) f16 T[64][72];
    const float* src = blockIdx.z == 0 ? Wq : blockIdx.z == 1 ? Wk : Wv;
    f16* dst = blockIdx.z == 0 ? WTq : blockIdx.z == 1 ? WTk : WTv;
    const int R = DMODEL, C = INNER;
    const int c0 = blockIdx.x * 64, r0 = blockIdx.y * 64;
    const int t = threadIdx.x;
    {
        int r = t >> 2, cb = (t & 3) * 16;
#pragma unroll
        for (int i = 0; i < 16; i += 4) {
            float4 v = *(const float4*)&src[(size_t)(r0 + r) * C + c0 + cb + i];
            T[cb + i + 0][r] = (f16)v.x;
            T[cb + i + 1][r] = (f16)v.y;
            T[cb + i + 2][r] = (f16)v.z;
            T[cb + i + 3][r] = (f16)v.w;
        }
    }
    __syncthreads();
    {
        int c = t >> 2, rb = (t & 3) * 16;
        f16* d = dst + (size_t)(c0 + c) * R + r0 + rb;
        *(f16x8*)d = *(const f16x8*)&T[c][rb];
        *(f16x8*)(d + 8) = *(const f16x8*)&T[c][rb + 8];
    }
}

// Same for Wo f32 [512][640] -> WoT f16 [640][512]
__global__ __launch_bounds__(256) void transpose_cvt(
    const float* __restrict__ src, f16* __restrict__ dst, int R, int C) {
    __shared__ __align__(16) f16 T[64][72];
    const int c0 = blockIdx.x * 64, r0 = blockIdx.y * 64;
    const int t = threadIdx.x;
    {
        int r = t >> 2, cb = (t & 3) * 16;
#pragma unroll
        for (int i = 0; i < 16; i += 4) {
            float4 v = *(const float4*)&src[(size_t)(r0 + r) * C + c0 + cb + i];
            T[cb + i + 0][r] = (f16)v.x;
            T[cb + i + 1][r] = (f16)v.y;
            T[cb + i + 2][r] = (f16)v.z;
            T[cb + i + 3][r] = (f16)v.w;
        }
    }
    __syncthreads();
    {
        int c = t >> 2, rb = (t & 3) * 16;
        f16* d = dst + (size_t)(c0 + c) * R + r0 + rb;
        *(f16x8*)d = *(const f16x8*)&T[c][rb];
        *(f16x8*)(d + 8) = *(const f16x8*)&T[c][rb + 8];
    }
}

// ---------------------------------------------------------------------------
// QKV projection, f16 MFMA, BK=64 with DOUBLE-BUFFERED staging: prefetch
// K-step t+1 into the alternate buffer before computing t; the end-of-iter
// barrier drains the prefetch AFTER compute (latency hidden). 1 barrier/iter.
// LDS 32KB -> 5 blocks/CU. Outputs: z=0 Q (prescaled) [h][n][d],
// z=1 K [h][n][d], z=2 V^T [h][d][n].
// ---------------------------------------------------------------------------
__global__ __launch_bounds__(256) void qkv_gemm16(
    const f16* __restrict__ xh,
    const f16* __restrict__ WTq, const f16* __restrict__ WTk,
    const f16* __restrict__ WTv,
    f16* __restrict__ q16, f16* __restrict__ k16, f16* __restrict__ vT16)
{
    __shared__ __align__(16) f16 Xs[2][4096];
    __shared__ __align__(16) f16 Ws[2][4096];
    f16 (*Cs)[72] = (f16(*)[72])&Xs[0][0];   // epilogue overlay (9216B)

    const int bx = blockIdx.x;               // head / N-tile
    const int by = blockIdx.y;               // M-tile
    const int bz = blockIdx.z;               // 0=Q 1=K 2=V
    const f16* WT = (bz == 0) ? WTq : (bz == 1) ? WTk : WTv;

    const int tid = threadIdx.x;
    const int w = tid >> 6, lane = tid & 63;
    const int lr = lane & 15, lc = lane >> 4;
    const int srow8 = lane >> 3;
    const int le = 8 * ((lane & 7) ^ srow8);
    const int swz0 = 8 * (lc ^ (lr & 7));
    const int swz1 = 8 * ((lc + 4) ^ (lr & 7));
    const int m0 = by * 64, n0 = bx * 64;

    f32x4 acc[4] = {};

    // prologue: stage K-step 0 into buffer 0
#pragma unroll
    for (int c = 0; c < 2; ++c) {
        const int cc = w * 2 + c;
        gl16(xh + (size_t)(m0 + cc * 8 + srow8) * DMODEL + le,
             &Xs[0][cc * 512]);
        gl16(WT + (size_t)(n0 + cc * 8 + srow8) * DMODEL + le,
             &Ws[0][cc * 512]);
    }
    __syncthreads();

    const int NS = DMODEL / 64;              // 10
    for (int s = 0; s < NS; ++s) {
        const int cur = s & 1;
        if (s < NS - 1) {                    // prefetch t+1 (async, drains at
            const int nb = cur ^ 1;          //  end-of-iter barrier)
            const int k0n = (s + 1) * 64;
#pragma unroll
            for (int c = 0; c < 2; ++c) {
                const int cc = w * 2 + c;
                gl16(xh + (size_t)(m0 + cc * 8 + srow8) * DMODEL + k0n + le,
                     &Xs[nb][cc * 512]);
                gl16(WT + (size_t)(n0 + cc * 8 + srow8) * DMODEL + k0n + le,
                     &Ws[nb][cc * 512]);
            }
        }
        f16x8 a0 = *(const f16x8*)&Xs[cur][(16 * w + lr) * 64 + swz0];
        f16x8 a1 = *(const f16x8*)&Xs[cur][(16 * w + lr) * 64 + swz1];
#pragma unroll
        for (int nt = 0; nt < 4; ++nt) {
            f16x8 b0 = *(const f16x8*)&Ws[cur][(nt * 16 + lr) * 64 + swz0];
            f16x8 b1 = *(const f16x8*)&Ws[cur][(nt * 16 + lr) * 64 + swz1];
            acc[nt] = MFMA16(a1, b1, MFMA16(a0, b0, acc[nt]));
        }
        __syncthreads();                     // prefetch landed; cur reads done
    }

    const float sc = (bz == 0) ? QSCALE : 1.0f;
    if (bz < 2) {
#pragma unroll
        for (int nt = 0; nt < 4; ++nt)
#pragma unroll
            for (int r = 0; r < 4; ++r)
                Cs[16 * w + lc * 4 + r][nt * 16 + lr] = (f16)(acc[nt][r] * sc);
    } else {
#pragma unroll
        for (int nt = 0; nt < 4; ++nt)
#pragma unroll
            for (int r = 0; r < 4; ++r)
                Cs[nt * 16 + lr][16 * w + lc * 4 + r] = (f16)acc[nt][r];
    }
    __syncthreads();
    {
        const int rr = tid >> 2, cb = (tid & 3) * 16;
        f16x8 v0 = *(const f16x8*)&Cs[rr][cb];
        f16x8 v1 = *(const f16x8*)&Cs[rr][cb + 8];
        f16* dst;
        if (bz == 0)
            dst = q16 + ((size_t)bx * NSEQ + m0 + rr) * DHEAD + cb;
        else if (bz == 1)
            dst = k16 + ((size_t)bx * NSEQ + m0 + rr) * DHEAD + cb;
        else
            dst = vT16 + ((size_t)bx * DHEAD + rr) * NSEQ + m0 + cb;
        *(f16x8*)dst = v0;
        *(f16x8*)(dst + 8) = v1;
    }
}

// ---------------------------------------------------------------------------
// Flash attention (round-8 fragment-reuse form, unchanged) + T5 setprio
// around the MFMA clusters. Block = (qtile 128, head, half); 4 waves; wave
// owns 32 q-rows. K/V double-buffered; ONE barrier/tile. Swapped QK^T,
// lane-local softmax (exp2 domain), exact defer-max. XCD remap: head == XCD.
// ---------------------------------------------------------------------------
__global__ __launch_bounds__(256, 2) void attn_fwd(
    const f16* __restrict__ q16, const f16* __restrict__ k16,
    const f16* __restrict__ vT16, f16* __restrict__ Opart,
    float* __restrict__ Ml)
{
    __shared__ __align__(16) f16 KsB[2][4096];   // [kv 64][d 64] swizzled
    __shared__ __align__(16) f16 VtB[2][4096];   // [d 64][kv 64] swizzled
    __shared__ __align__(16) f16 Ps[8192];       // [q 128][kv 64] swizzled

    const int lin = blockIdx.x + 32 * blockIdx.y + 256 * blockIdx.z;
    const int h  = lin & 7;
    const int qb = (lin >> 3) & 31;              // q-tile of 128 rows
    const int sp = lin >> 8;                     // kv half 0/1

    const int tid = threadIdx.x;
    const int w = tid >> 6, lane = tid & 63;
    const int lr = lane & 15, lc = lane >> 4;
    const int srow8 = lane >> 3;
    const int le = 8 * ((lane & 7) ^ srow8);
    const int swz0 = 8 * (lc ^ (lr & 7));
    const int swz1 = 8 * ((lc + 4) ^ (lr & 7));

    const f16* kp = k16 + ((size_t)h * NSEQ + sp * (NSEQ / KVSPLIT)) * DHEAD;
    const f16* vp = vT16 + (size_t)h * DHEAD * NSEQ + sp * (NSEQ / KVSPLIT);

    // Q fragments: wave rows qb*128 + 32w + 16g + lr, g=0,1 (prescaled)
    f16x8 qf[2][2];
#pragma unroll
    for (int g = 0; g < 2; ++g) {
        const f16* qp = q16 +
            ((size_t)h * NSEQ + qb * 128 + 32 * w + 16 * g + lr) * DHEAD;
        qf[g][0] = *(const f16x8*)&qp[lc * 8];
        qf[g][1] = *(const f16x8*)&qp[32 + lc * 8];
    }

    float m_run[2] = {-INFINITY, -INFINITY}, l_run[2] = {0.f, 0.f};
    f32x4 o[2][4] = {};

    // stage tile 0 into buffer 0 (wave w: chunks 2w, 2w+1 of each)
#pragma unroll
    for (int c = 0; c < 2; ++c) {
        const int cc = 2 * w + c;
        gl16(kp + (size_t)(cc * 8 + srow8) * DHEAD + le, &KsB[0][cc * 512]);
        gl16(vp + (size_t)(cc * 8 + srow8) * NSEQ + le, &VtB[0][cc * 512]);
    }
    __syncthreads();

    const int NT = NSEQ / KVSPLIT / 64;          // 32
    for (int kt = 0; kt < NT; ++kt) {
        const int cur = kt & 1;
        if (kt < NT - 1) {                       // prefetch t+1 (async)
            const int nb = cur ^ 1;
#pragma unroll
            for (int c = 0; c < 2; ++c) {
                const int cc = 2 * w + c;
                gl16(kp + (size_t)((kt + 1) * 64 + cc * 8 + srow8) * DHEAD + le,
                     &KsB[nb][cc * 512]);
                gl16(vp + (size_t)(cc * 8 + srow8) * NSEQ + (kt + 1) * 64 + le,
                     &VtB[nb][cc * 512]);
            }
        }

        // ---- S^T = K Q^T: lane holds S[q = group row lr][kv = 16t+4lc+r]
        f32x4 s[2][4];
        const f32x4 z4 = {0.f, 0.f, 0.f, 0.f};
        __builtin_amdgcn_s_setprio(1);
#pragma unroll
        for (int t = 0; t < 4; ++t) {
            f16x8 ka = *(const f16x8*)&KsB[cur][(t * 16 + lr) * 64 + swz0];
            f16x8 kb = *(const f16x8*)&KsB[cur][(t * 16 + lr) * 64 + swz1];
#pragma unroll
            for (int g = 0; g < 2; ++g)
                s[g][t] = MFMA16(kb, qf[g][1], MFMA16(ka, qf[g][0], z4));
        }
        __builtin_amdgcn_s_setprio(0);

        // ---- lane-local online softmax (exp2 domain), exact defer-max
        float pm[2];
#pragma unroll
        for (int g = 0; g < 2; ++g) {
            float m = s[g][0][0];
#pragma unroll
            for (int t = 0; t < 4; ++t)
#pragma unroll
                for (int r = 0; r < 4; ++r) m = fmaxf(m, s[g][t][r]);
            m = fmaxf(m, __shfl_xor(m, 16));
            m = fmaxf(m, __shfl_xor(m, 32));
            pm[g] = m;
        }
        if (__any((pm[0] > m_run[0]) | (pm[1] > m_run[1]))) {
#pragma unroll
            for (int g = 0; g < 2; ++g) {
                const float mn = fmaxf(m_run[g], pm[g]);
                const float al = __builtin_amdgcn_exp2f(m_run[g] - mn);
                m_run[g] = mn;
                l_run[g] *= al;
#pragma unroll
                for (int dt = 0; dt < 4; ++dt) o[g][dt] *= al;
            }
        }
#pragma unroll
        for (int g = 0; g < 2; ++g) {
            float ps = 0.f;
#pragma unroll
            for (int t = 0; t < 4; ++t)
#pragma unroll
                for (int r = 0; r < 4; ++r) {
                    s[g][t][r] = __builtin_amdgcn_exp2f(s[g][t][r] - m_run[g]);
                    ps += s[g][t][r];
                }
            ps += __shfl_xor(ps, 16);
            ps += __shfl_xor(ps, 32);
            l_run[g] += ps;
        }

        // ---- P -> own strip (rows 32w+16g+lr), swizzled like reads
#pragma unroll
        for (int g = 0; g < 2; ++g) {
            const int row = 32 * w + 16 * g + lr;
#pragma unroll
            for (int t = 0; t < 4; ++t) {
                f16x4 pk = {(f16)s[g][t][0], (f16)s[g][t][1],
                            (f16)s[g][t][2], (f16)s[g][t][3]};
                const int col = (16 * t + 4 * lc) ^ ((lr & 7) << 3);
                *(f16x4*)&Ps[row * 64 + col] = pk;
            }
        }

        // ---- O^T += V^T P^T (V fragments reused across both q-groups)
        f16x8 pb[2][2];
#pragma unroll
        for (int g = 0; g < 2; ++g) {
            const int row = 32 * w + 16 * g + lr;
            pb[g][0] = *(const f16x8*)&Ps[row * 64 + swz0];
            pb[g][1] = *(const f16x8*)&Ps[row * 64 + swz1];
        }
        __builtin_amdgcn_s_setprio(1);
#pragma unroll
        for (int dt = 0; dt < 4; ++dt) {
            f16x8 va0 = *(const f16x8*)&VtB[cur][(dt * 16 + lr) * 64 + swz0];
            f16x8 va1 = *(const f16x8*)&VtB[cur][(dt * 16 + lr) * 64 + swz1];
#pragma unroll
            for (int g = 0; g < 2; ++g)
                o[g][dt] = MFMA16(va1, pb[g][1], MFMA16(va0, pb[g][0], o[g][dt]));
        }
        __builtin_amdgcn_s_setprio(0);
        __syncthreads();   // prefetch landed; all reads of buf[cur] done
    }

    // ---- epilogue: per-split normalized O (f16) + (m,l)
#pragma unroll
    for (int g = 0; g < 2; ++g) {
        const float linv = 1.0f / l_run[g];
        const size_t qg = (size_t)qb * 128 + 32 * w + 16 * g + lr;
        f16* ob = Opart + (((size_t)(sp * 8 + h)) * NSEQ + qg) * DHEAD;
#pragma unroll
        for (int dt = 0; dt < 4; ++dt) {
            f16x4 ov = {(f16)(o[g][dt][0] * linv), (f16)(o[g][dt][1] * linv),
                        (f16)(o[g][dt][2] * linv), (f16)(o[g][dt][3] * linv)};
            *(f16x4*)&ob[dt * 16 + 4 * lc] = ov;
        }
        if (lc == 0) {
            float2 ml = make_float2(m_run[g], l_run[g]);
            *(float2*)&Ml[(((size_t)(sp * 8 + h)) * NSEQ + qg) * 2] = ml;
        }
    }
}

// ---------------------------------------------------------------------------
// Output projection + 2-way kv-split combine, DOUBLE-BUFFERED:
// B (WoT) prefetched via gl16; A (combined partials) staged T14-style —
// global loads for step t+1 issued before compute(t), combine+ds_write after.
// K-step s8 == head. LDS 32KB.
// ---------------------------------------------------------------------------
__global__ __launch_bounds__(256) void out_gemm16(
    const f16* __restrict__ Opart, const float* __restrict__ Ml,
    const f16* __restrict__ WoT,
    const float* __restrict__ bias, float* __restrict__ C)
{
    __shared__ __align__(16) f16 Xs[2][4096];
    __shared__ __align__(16) f16 Ws[2][4096];

    const int bx = blockIdx.x;   // N-tile 0..9
    const int by = blockIdx.y;   // M-tile 0..63
    const int tid = threadIdx.x;
    const int w = tid >> 6, lane = tid & 63;
    const int lr = lane & 15, lc = lane >> 4;
    const int srow8 = lane >> 3;
    const int j = lane & 7;
    const int le = 8 * (j ^ srow8);
    const int swz0 = 8 * (lc ^ (lr & 7));
    const int swz1 = 8 * ((lc + 4) ^ (lr & 7));
    const int m0 = by * 64, n0 = bx * 64;

    // A-staging helper indices (two rows per thread: cc = 2w + c)
    const int row_c0 = (2 * w + 0) * 8 + srow8;
    const int row_c1 = (2 * w + 1) * 8 + srow8;

    f32x4 acc[4] = {};

    // combine step s8 partials for row `row` into an f16x8
    auto combine = [&](int s8, int row) -> f16x8 {
        const size_t q = (size_t)m0 + row;
        f16x8 o0 = *(const f16x8*)&Opart[((size_t)s8 * NSEQ + q) * DHEAD + 8 * j];
        f16x8 o1 = *(const f16x8*)&Opart[((size_t)(8 + s8) * NSEQ + q) * DHEAD + 8 * j];
        float2 ml0 = *(const float2*)&Ml[((size_t)s8 * NSEQ + q) * 2];
        float2 ml1 = *(const float2*)&Ml[((size_t)(8 + s8) * NSEQ + q) * 2];
        const float mx = fmaxf(ml0.x, ml1.x);
        float w0 = ml0.y * __builtin_amdgcn_exp2f(ml0.x - mx);
        float w1 = ml1.y * __builtin_amdgcn_exp2f(ml1.x - mx);
        const float inv = 1.0f / (w0 + w1);
        w0 *= inv; w1 *= inv;
        f16x8 a8;
#pragma unroll
        for (int e = 0; e < 8; ++e)
            a8[e] = (f16)((float)o0[e] * w0 + (float)o1[e] * w1);
        return a8;
    };

    // prologue: stage step 0 into buffer 0
    gl16(WoT + (size_t)(n0 + row_c0) * INNER + le, &Ws[0][(2 * w + 0) * 512]);
    gl16(WoT + (size_t)(n0 + row_c1) * INNER + le, &Ws[0][(2 * w + 1) * 512]);
    *(f16x8*)&Xs[0][row_c0 * 64 + 8 * (j ^ (row_c0 & 7))] = combine(0, row_c0);
    *(f16x8*)&Xs[0][row_c1 * 64 + 8 * (j ^ (row_c1 & 7))] = combine(0, row_c1);
    __syncthreads();

    for (int s8 = 0; s8 < 8; ++s8) {
        const int cur = s8 & 1;
        f16x8 a8n_0, a8n_1;
        const bool pre = (s8 < 7);
        if (pre) {                           // issue next-step staging early
            const int nb = cur ^ 1;
            const int k0n = (s8 + 1) * 64;
            gl16(WoT + (size_t)(n0 + row_c0) * INNER + k0n + le,
                 &Ws[nb][(2 * w + 0) * 512]);
            gl16(WoT + (size_t)(n0 + row_c1) * INNER + k0n + le,
                 &Ws[nb][(2 * w + 1) * 512]);
            a8n_0 = combine(s8 + 1, row_c0); // loads overlap GEMM below
            a8n_1 = combine(s8 + 1, row_c1);
        }
        f16x8 a0 = *(const f16x8*)&Xs[cur][(16 * w + lr) * 64 + swz0];
        f16x8 a1 = *(const f16x8*)&Xs[cur][(16 * w + lr) * 64 + swz1];
#pragma unroll
        for (int nt = 0; nt < 4; ++nt) {
            f16x8 b0 = *(const f16x8*)&Ws[cur][(nt * 16 + lr) * 64 + swz0];
            f16x8 b1 = *(const f16x8*)&Ws[cur][(nt * 16 + lr) * 64 + swz1];
            acc[nt] = MFMA16(a1, b1, MFMA16(a0, b0, acc[nt]));
        }
        if (pre) {                           // write-late into alternate buf
            const int nb = cur ^ 1;
            *(f16x8*)&Xs[nb][row_c0 * 64 + 8 * (j ^ (row_c0 & 7))] = a8n_0;
            *(f16x8*)&Xs[nb][row_c1 * 64 + 8 * (j ^ (row_c1 & 7))] = a8n_1;
        }
        __syncthreads();                     // staging landed; cur reads done
    }

#pragma unroll
    for (int nt = 0; nt < 4; ++nt) {
        const float b = bias[n0 + nt * 16 + lr];
#pragma unroll
        for (int r = 0; r < 4; ++r)
            C[(size_t)(m0 + 16 * w + lc * 4 + r) * DMODEL + n0 + nt * 16 + lr] =
                acc[nt][r] + b;
    }
}

extern "C" void kernel_launch(void* const* d_in, const int* in_sizes, int n_in,
                              void* d_out, int out_size, void* d_ws, size_t ws_size,
                              hipStream_t stream) {
    const float* x  = (const float*)d_in[0];
    const float* Wq = (const float*)d_in[1];
    const float* Wk = (const float*)d_in[2];
    const float* Wv = (const float*)d_in[3];
    const float* Wo = (const float*)d_in[4];
    const float* bo = (const float*)d_in[5];
    float* out = (float*)d_out;

    // Workspace layout (bytes). Opart overlays xh/WTq/WTk/WTv (disjoint
    // lifetimes: xh/WT die at qkv_gemm16 end; Opart born in attn_fwd).
    char* base = (char*)d_ws;
    f16*   Opart = (f16*)base;                   // 2*8*4096*64*2 = 8,388,608
    f16*   xh    = (f16*)base;                   // 5,242,880
    f16*   WTq   = xh + (size_t)NSEQ * DMODEL;
    f16*   WTk   = WTq + (size_t)INNER * DMODEL;
    f16*   WTv   = WTk + (size_t)INNER * DMODEL; // ends 7,208,960 < 8,388,608
    float* Ml    = (float*)(base + 8388608);     // 2*8*4096*2*4 = 524,288
    f16*   WoT   = (f16*)(base + 8912896);       // 655,360
    f16*   q16   = (f16*)(base + 9568256);       // 4,194,304
    f16*   k16   = q16 + (size_t)NHEAD * NSEQ * DHEAD;
    f16*   vT16  = k16 + (size_t)NHEAD * NSEQ * DHEAD;  // ends 22,151,168 B

    cvt_x<<<NSEQ * DMODEL / (256 * 8), 256, 0, stream>>>(x, xh);
    transpose_cvt3<<<dim3(INNER / 64, DMODEL / 64, 3), 256, 0, stream>>>(
        Wq, Wk, Wv, WTq, WTk, WTv);
    transpose_cvt<<<dim3(DMODEL / 64, INNER / 64), 256, 0, stream>>>(
        Wo, WoT, INNER, DMODEL);

    qkv_gemm16<<<dim3(NHEAD, NSEQ / 64, 3), 256, 0, stream>>>(
        xh, WTq, WTk, WTv, q16, k16, vT16);
    attn_fwd<<<dim3(NSEQ / 128, NHEAD, KVSPLIT), 256, 0, stream>>>(
        q16, k16, vT16, Opart, Ml);
    out_gemm16<<<dim3(DMODEL / 64, NSEQ / 64), 256, 0, stream>>>(
        Opart, Ml, WoT, bo, out);
}

// Round 10
// 170.011 us; speedup vs baseline: 1.0442x; 1.0442x over previous
//
#include <hip/hip_runtime.h>
#include <math.h>

#define NSEQ   4096
#define DMODEL 640
#define NHEAD  8
#define DHEAD  64
#define INNER  512   // NHEAD*DHEAD
#define KVSPLIT 2

typedef _Float16 f16;
typedef _Float16 f16x8 __attribute__((ext_vector_type(8)));
typedef _Float16 f16x4 __attribute__((ext_vector_type(4)));
typedef float    f32x4 __attribute__((ext_vector_type(4)));

#define MFMA16(a, b, c) __builtin_amdgcn_mfma_f32_16x16x32_f16((a), (b), (c), 0, 0, 0)

// softmax scale 1/8 folded with log2(e): softmax runs in exp2 domain
#define QSCALE 0.18033688011112042f

// global -> LDS direct copy, 16B/lane, wave-uniform LDS base.
__device__ __forceinline__ void gl16(const f16* g, f16* l) {
    __builtin_amdgcn_global_load_lds(
        (const __attribute__((address_space(1))) unsigned int*)g,
        (__attribute__((address_space(3))) unsigned int*)l, 16, 0, 0);
}

// ---------------------------------------------------------------------------
// Prep: x (f32) -> xh (f16), 8 elems/thread
// ---------------------------------------------------------------------------
__global__ __launch_bounds__(256) void cvt_x(const float* __restrict__ x,
                                             f16* __restrict__ xh) {
    int i = (blockIdx.x * 256 + threadIdx.x) * 8;
    float4 a = *(const float4*)&x[i];
    float4 b = *(const float4*)&x[i + 4];
    f16x8 o = {(f16)a.x, (f16)a.y, (f16)a.z, (f16)a.w,
               (f16)b.x, (f16)b.y, (f16)b.z, (f16)b.w};
    *(f16x8*)&xh[i] = o;
}

// ---------------------------------------------------------------------------
// Prep: transpose+convert all four weights in ONE launch.
// z=0..2: Wq/Wk/Wv f32 [640][512] -> f16 [512][640]; z=3: Wo [512][640]->[640][512]
// ---------------------------------------------------------------------------
__global__ __launch_bounds__(256) void transpose_cvtW(
    const float* __restrict__ Wq, const float* __restrict__ Wk,
    const float* __restrict__ Wv, const float* __restrict__ Wo,
    f16* __restrict__ WTq, f16* __restrict__ WTk, f16* __restrict__ WTv,
    f16* __restrict__ WoT) {
    __shared__ __align__(16) f16 T[64][72];
    const int bz = blockIdx.z;
    const float* src = bz == 0 ? Wq : bz == 1 ? Wk : bz == 2 ? Wv : Wo;
    f16* dst = bz == 0 ? WTq : bz == 1 ? WTk : bz == 2 ? WTv : WoT;
    const int R = (bz < 3) ? DMODEL : INNER;   // src rows
    const int C = (bz < 3) ? INNER : DMODEL;   // src cols
    const int c0 = blockIdx.x * 64, r0 = blockIdx.y * 64;
    if (c0 >= C || r0 >= R) return;            // block-uniform early out
    const int t = threadIdx.x;
    {
        int r = t >> 2, cb = (t & 3) * 16;
#pragma unroll
        for (int i = 0; i < 16; i += 4) {
            float4 v = *(const float4*)&src[(size_t)(r0 + r) * C + c0 + cb + i];
            T[cb + i + 0][r] = (f16)v.x;
            T[cb + i + 1][r] = (f16)v.y;
            T[cb + i + 2][r] = (f16)v.z;
            T[cb + i + 3][r] = (f16)v.w;
        }
    }
    __syncthreads();
    {
        int c = t >> 2, rb = (t & 3) * 16;
        f16* d = dst + (size_t)(c0 + c) * R + r0 + rb;
        *(f16x8*)d = *(const f16x8*)&T[c][rb];
        *(f16x8*)(d + 8) = *(const f16x8*)&T[c][rb + 8];
    }
}

// ---------------------------------------------------------------------------
// QKV projection, f16 MFMA, FRAGMENT-REUSE tiling: M-tile 128, N-tile 64
// (=head), K-step 64, 4 waves; wave owns 32 rows (2 groups of 16) so each
// B-fragment read feeds 2 MFMAs: 12 b128 reads per 32 MFMA (was 10 per 16).
// Grid (8,32,3) = 768 blocks = exactly 3/CU. Single-buffered staging (dbuf
// proven null in r9); LDS 24KB + flat epilogue overlay.
// Outputs: z=0 Q (prescaled) [h][n][d], z=1 K [h][n][d], z=2 V^T [h][d][n].
// ---------------------------------------------------------------------------
__global__ __launch_bounds__(256) void qkv_gemm16(
    const f16* __restrict__ xh,
    const f16* __restrict__ WTq, const f16* __restrict__ WTk,
    const f16* __restrict__ WTv,
    f16* __restrict__ q16, f16* __restrict__ k16, f16* __restrict__ vT16)
{
    __shared__ __align__(16) f16 S[12288];   // A: [0,8192) B: [8192,12288)
    f16* Xs = S;                              // [128 rows][64 cols]
    f16* Ws = S + 8192;                       // [64][64]

    const int bx = blockIdx.x;               // head / N-tile
    const int by = blockIdx.y;               // M-tile (128 rows)
    const int bz = blockIdx.z;               // 0=Q 1=K 2=V
    const f16* WT = (bz == 0) ? WTq : (bz == 1) ? WTk : WTv;

    const int tid = threadIdx.x;
    const int w = tid >> 6, lane = tid & 63;
    const int lr = lane & 15, lc = lane >> 4;
    const int srow8 = lane >> 3;
    const int le = 8 * ((lane & 7) ^ srow8);
    const int swz0 = 8 * (lc ^ (lr & 7));
    const int swz1 = 8 * ((lc + 4) ^ (lr & 7));
    const int m0 = by * 128, n0 = bx * 64;

    f32x4 acc[2][4] = {};

    for (int s = 0; s < DMODEL / 64; ++s) {
        const int k0 = s * 64;
        // A: 16 chunks of 8 rows; wave w stages cc = 4w..4w+3
#pragma unroll
        for (int c = 0; c < 4; ++c) {
            const int cc = 4 * w + c;
            gl16(xh + (size_t)(m0 + cc * 8 + srow8) * DMODEL + k0 + le,
                 &Xs[cc * 512]);
        }
        // B: 8 chunks; wave w stages cc = 2w, 2w+1
#pragma unroll
        for (int c = 0; c < 2; ++c) {
            const int cc = 2 * w + c;
            gl16(WT + (size_t)(n0 + cc * 8 + srow8) * DMODEL + k0 + le,
                 &Ws[cc * 512]);
        }
        __syncthreads();
        f16x8 a0[2], a1[2];
#pragma unroll
        for (int g = 0; g < 2; ++g) {
            const int row = 32 * w + 16 * g + lr;
            a0[g] = *(const f16x8*)&Xs[row * 64 + swz0];
            a1[g] = *(const f16x8*)&Xs[row * 64 + swz1];
        }
#pragma unroll
        for (int nt = 0; nt < 4; ++nt) {
            f16x8 b0 = *(const f16x8*)&Ws[(nt * 16 + lr) * 64 + swz0];
            f16x8 b1 = *(const f16x8*)&Ws[(nt * 16 + lr) * 64 + swz1];
#pragma unroll
            for (int g = 0; g < 2; ++g)
                acc[g][nt] = MFMA16(a1[g], b1, MFMA16(a0[g], b0, acc[g][nt]));
        }
        __syncthreads();
    }

    // Epilogue via flat LDS overlay (24KB): coalesced f16 stores.
    const float sc = (bz == 0) ? QSCALE : 1.0f;
    if (bz < 2) {
        // Cs[128][72]: row = m-offset, col = head-dim
#pragma unroll
        for (int g = 0; g < 2; ++g)
#pragma unroll
            for (int nt = 0; nt < 4; ++nt)
#pragma unroll
                for (int r = 0; r < 4; ++r)
                    S[(32 * w + 16 * g + 4 * lc + r) * 72 + nt * 16 + lr] =
                        (f16)(acc[g][nt][r] * sc);
        __syncthreads();
        f16* ob = ((bz == 0) ? q16 : k16) + (size_t)bx * NSEQ * DHEAD;
#pragma unroll
        for (int p = 0; p < 2; ++p) {
            const int rr = p * 64 + (tid >> 2), cb = (tid & 3) * 16;
            f16* dst = ob + (size_t)(m0 + rr) * DHEAD + cb;
            *(f16x8*)dst = *(const f16x8*)&S[rr * 72 + cb];
            *(f16x8*)(dst + 8) = *(const f16x8*)&S[rr * 72 + cb + 8];
        }
    } else {
        // Cs[64][136]: row = head-dim d, col = m-offset (transposed)
#pragma unroll
        for (int g = 0; g < 2; ++g)
#pragma unroll
            for (int nt = 0; nt < 4; ++nt)
#pragma unroll
                for (int r = 0; r < 4; ++r)
                    S[(nt * 16 + lr) * 136 + 32 * w + 16 * g + 4 * lc + r] =
                        (f16)acc[g][nt][r];
        __syncthreads();
        const int rr = tid >> 2, cb = (tid & 3) * 32;
        f16* dst = vT16 + ((size_t)bx * DHEAD + rr) * NSEQ + m0 + cb;
        *(f16x8*)dst        = *(const f16x8*)&S[rr * 136 + cb];
        *(f16x8*)(dst + 8)  = *(const f16x8*)&S[rr * 136 + cb + 8];
        *(f16x8*)(dst + 16) = *(const f16x8*)&S[rr * 136 + cb + 16];
        *(f16x8*)(dst + 24) = *(const f16x8*)&S[rr * 136 + cb + 24];
    }
}

// ---------------------------------------------------------------------------
// Flash attention (round-8 fragment-reuse form, exact revert — no setprio).
// Block = (qtile 128, head, half); 4 waves; wave owns 32 q-rows. K/V
// double-buffered; ONE barrier/tile. Swapped QK^T, lane-local softmax
// (exp2 domain), exact defer-max. XCD remap: head == XCD.
// ---------------------------------------------------------------------------
__global__ __launch_bounds__(256, 2) void attn_fwd(
    const f16* __restrict__ q16, const f16* __restrict__ k16,
    const f16* __restrict__ vT16, f16* __restrict__ Opart,
    float* __restrict__ Ml)
{
    __shared__ __align__(16) f16 KsB[2][4096];   // [kv 64][d 64] swizzled
    __shared__ __align__(16) f16 VtB[2][4096];   // [d 64][kv 64] swizzled
    __shared__ __align__(16) f16 Ps[8192];       // [q 128][kv 64] swizzled

    const int lin = blockIdx.x + 32 * blockIdx.y + 256 * blockIdx.z;
    const int h  = lin & 7;
    const int qb = (lin >> 3) & 31;              // q-tile of 128 rows
    const int sp = lin >> 8;                     // kv half 0/1

    const int tid = threadIdx.x;
    const int w = tid >> 6, lane = tid & 63;
    const int lr = lane & 15, lc = lane >> 4;
    const int srow8 = lane >> 3;
    const int le = 8 * ((lane & 7) ^ srow8);
    const int swz0 = 8 * (lc ^ (lr & 7));
    const int swz1 = 8 * ((lc + 4) ^ (lr & 7));

    const f16* kp = k16 + ((size_t)h * NSEQ + sp * (NSEQ / KVSPLIT)) * DHEAD;
    const f16* vp = vT16 + (size_t)h * DHEAD * NSEQ + sp * (NSEQ / KVSPLIT);

    // Q fragments: wave rows qb*128 + 32w + 16g + lr, g=0,1 (prescaled)
    f16x8 qf[2][2];
#pragma unroll
    for (int g = 0; g < 2; ++g) {
        const f16* qp = q16 +
            ((size_t)h * NSEQ + qb * 128 + 32 * w + 16 * g + lr) * DHEAD;
        qf[g][0] = *(const f16x8*)&qp[lc * 8];
        qf[g][1] = *(const f16x8*)&qp[32 + lc * 8];
    }

    float m_run[2] = {-INFINITY, -INFINITY}, l_run[2] = {0.f, 0.f};
    f32x4 o[2][4] = {};

    // stage tile 0 into buffer 0 (wave w: chunks 2w, 2w+1 of each)
#pragma unroll
    for (int c = 0; c < 2; ++c) {
        const int cc = 2 * w + c;
        gl16(kp + (size_t)(cc * 8 + srow8) * DHEAD + le, &KsB[0][cc * 512]);
        gl16(vp + (size_t)(cc * 8 + srow8) * NSEQ + le, &VtB[0][cc * 512]);
    }
    __syncthreads();

    const int NT = NSEQ / KVSPLIT / 64;          // 32
    for (int kt = 0; kt < NT; ++kt) {
        const int cur = kt & 1;
        if (kt < NT - 1) {                       // prefetch t+1 (async)
            const int nb = cur ^ 1;
#pragma unroll
            for (int c = 0; c < 2; ++c) {
                const int cc = 2 * w + c;
                gl16(kp + (size_t)((kt + 1) * 64 + cc * 8 + srow8) * DHEAD + le,
                     &KsB[nb][cc * 512]);
                gl16(vp + (size_t)(cc * 8 + srow8) * NSEQ + (kt + 1) * 64 + le,
                     &VtB[nb][cc * 512]);
            }
        }

        // ---- S^T = K Q^T: lane holds S[q = group row lr][kv = 16t+4lc+r]
        f32x4 s[2][4];
        const f32x4 z4 = {0.f, 0.f, 0.f, 0.f};
#pragma unroll
        for (int t = 0; t < 4; ++t) {
            f16x8 ka = *(const f16x8*)&KsB[cur][(t * 16 + lr) * 64 + swz0];
            f16x8 kb = *(const f16x8*)&KsB[cur][(t * 16 + lr) * 64 + swz1];
#pragma unroll
            for (int g = 0; g < 2; ++g)
                s[g][t] = MFMA16(kb, qf[g][1], MFMA16(ka, qf[g][0], z4));
        }

        // ---- lane-local online softmax (exp2 domain), exact defer-max
        float pm[2];
#pragma unroll
        for (int g = 0; g < 2; ++g) {
            float m = s[g][0][0];
#pragma unroll
            for (int t = 0; t < 4; ++t)
#pragma unroll
                for (int r = 0; r < 4; ++r) m = fmaxf(m, s[g][t][r]);
            m = fmaxf(m, __shfl_xor(m, 16));
            m = fmaxf(m, __shfl_xor(m, 32));
            pm[g] = m;
        }
        if (__any((pm[0] > m_run[0]) | (pm[1] > m_run[1]))) {
#pragma unroll
            for (int g = 0; g < 2; ++g) {
                const float mn = fmaxf(m_run[g], pm[g]);
                const float al = __builtin_amdgcn_exp2f(m_run[g] - mn);
                m_run[g] = mn;
                l_run[g] *= al;
#pragma unroll
                for (int dt = 0; dt < 4; ++dt) o[g][dt] *= al;
            }
        }
#pragma unroll
        for (int g = 0; g < 2; ++g) {
            float ps = 0.f;
#pragma unroll
            for (int t = 0; t < 4; ++t)
#pragma unroll
                for (int r = 0; r < 4; ++r) {
                    s[g][t][r] = __builtin_amdgcn_exp2f(s[g][t][r] - m_run[g]);
                    ps += s[g][t][r];
                }
            ps += __shfl_xor(ps, 16);
            ps += __shfl_xor(ps, 32);
            l_run[g] += ps;
        }

        // ---- P -> own strip (rows 32w+16g+lr), swizzled like reads
#pragma unroll
        for (int g = 0; g < 2; ++g) {
            const int row = 32 * w + 16 * g + lr;
#pragma unroll
            for (int t = 0; t < 4; ++t) {
                f16x4 pk = {(f16)s[g][t][0], (f16)s[g][t][1],
                            (f16)s[g][t][2], (f16)s[g][t][3]};
                const int col = (16 * t + 4 * lc) ^ ((lr & 7) << 3);
                *(f16x4*)&Ps[row * 64 + col] = pk;
            }
        }

        // ---- O^T += V^T P^T (V fragments reused across both q-groups)
        f16x8 pb[2][2];
#pragma unroll
        for (int g = 0; g < 2; ++g) {
            const int row = 32 * w + 16 * g + lr;
            pb[g][0] = *(const f16x8*)&Ps[row * 64 + swz0];
            pb[g][1] = *(const f16x8*)&Ps[row * 64 + swz1];
        }
#pragma unroll
        for (int dt = 0; dt < 4; ++dt) {
            f16x8 va0 = *(const f16x8*)&VtB[cur][(dt * 16 + lr) * 64 + swz0];
            f16x8 va1 = *(const f16x8*)&VtB[cur][(dt * 16 + lr) * 64 + swz1];
#pragma unroll
            for (int g = 0; g < 2; ++g)
                o[g][dt] = MFMA16(va1, pb[g][1], MFMA16(va0, pb[g][0], o[g][dt]));
        }
        __syncthreads();   // prefetch landed; all reads of buf[cur] done
    }

    // ---- epilogue: per-split normalized O (f16) + (m,l)
#pragma unroll
    for (int g = 0; g < 2; ++g) {
        const float linv = 1.0f / l_run[g];
        const size_t qg = (size_t)qb * 128 + 32 * w + 16 * g + lr;
        f16* ob = Opart + (((size_t)(sp * 8 + h)) * NSEQ + qg) * DHEAD;
#pragma unroll
        for (int dt = 0; dt < 4; ++dt) {
            f16x4 ov = {(f16)(o[g][dt][0] * linv), (f16)(o[g][dt][1] * linv),
                        (f16)(o[g][dt][2] * linv), (f16)(o[g][dt][3] * linv)};
            *(f16x4*)&ob[dt * 16 + 4 * lc] = ov;
        }
        if (lc == 0) {
            float2 ml = make_float2(m_run[g], l_run[g]);
            *(float2*)&Ml[(((size_t)(sp * 8 + h)) * NSEQ + qg) * 2] = ml;
        }
    }
}

// ---------------------------------------------------------------------------
// Output projection + 2-way kv-split combine (round-8 form, exact revert).
// K-step s8 == head.
// ---------------------------------------------------------------------------
__global__ __launch_bounds__(256) void out_gemm16(
    const f16* __restrict__ Opart, const float* __restrict__ Ml,
    const f16* __restrict__ WoT,
    const float* __restrict__ bias, float* __restrict__ C)
{
    __shared__ __align__(16) f16 Xs[4096];
    __shared__ __align__(16) f16 Ws[4096];

    const int bx = blockIdx.x;   // N-tile 0..9
    const int by = blockIdx.y;   // M-tile 0..63
    const int tid = threadIdx.x;
    const int w = tid >> 6, lane = tid & 63;
    const int lr = lane & 15, lc = lane >> 4;
    const int srow8 = lane >> 3;
    const int j = lane & 7;
    const int le = 8 * (j ^ srow8);
    const int swz0 = 8 * (lc ^ (lr & 7));
    const int swz1 = 8 * ((lc + 4) ^ (lr & 7));
    const int m0 = by * 64, n0 = bx * 64;

    f32x4 acc[4] = {};

    for (int s8 = 0; s8 < 8; ++s8) {         // K-step == head
        const int k0 = s8 * 64;
#pragma unroll
        for (int c = 0; c < 2; ++c) {
            const int cc = w * 2 + c;
            gl16(WoT + (size_t)(n0 + cc * 8 + srow8) * INNER + k0 + le,
                 &Ws[cc * 512]);
            // A: combine the two normalized partials in registers
            const int row = cc * 8 + srow8;
            const size_t q = (size_t)m0 + row;
            f16x8 o0 = *(const f16x8*)&Opart[((size_t)s8 * NSEQ + q) * DHEAD + 8 * j];
            f16x8 o1 = *(const f16x8*)&Opart[((size_t)(8 + s8) * NSEQ + q) * DHEAD + 8 * j];
            float2 ml0 = *(const float2*)&Ml[((size_t)s8 * NSEQ + q) * 2];
            float2 ml1 = *(const float2*)&Ml[((size_t)(8 + s8) * NSEQ + q) * 2];
            const float mx = fmaxf(ml0.x, ml1.x);
            float w0 = ml0.y * __builtin_amdgcn_exp2f(ml0.x - mx);
            float w1 = ml1.y * __builtin_amdgcn_exp2f(ml1.x - mx);
            const float inv = 1.0f / (w0 + w1);
            w0 *= inv; w1 *= inv;
            f16x8 a8;
#pragma unroll
            for (int e = 0; e < 8; ++e)
                a8[e] = (f16)((float)o0[e] * w0 + (float)o1[e] * w1);
            *(f16x8*)&Xs[row * 64 + 8 * (j ^ (row & 7))] = a8;
        }
        __syncthreads();
        f16x8 a0 = *(const f16x8*)&Xs[(16 * w + lr) * 64 + swz0];
        f16x8 a1 = *(const f16x8*)&Xs[(16 * w + lr) * 64 + swz1];
#pragma unroll
        for (int nt = 0; nt < 4; ++nt) {
            f16x8 b0 = *(const f16x8*)&Ws[(nt * 16 + lr) * 64 + swz0];
            f16x8 b1 = *(const f16x8*)&Ws[(nt * 16 + lr) * 64 + swz1];
            acc[nt] = MFMA16(a1, b1, MFMA16(a0, b0, acc[nt]));
        }
        __syncthreads();
    }

#pragma unroll
    for (int nt = 0; nt < 4; ++nt) {
        const float b = bias[n0 + nt * 16 + lr];
#pragma unroll
        for (int r = 0; r < 4; ++r)
            C[(size_t)(m0 + 16 * w + lc * 4 + r) * DMODEL + n0 + nt * 16 + lr] =
                acc[nt][r] + b;
    }
}

extern "C" void kernel_launch(void* const* d_in, const int* in_sizes, int n_in,
                              void* d_out, int out_size, void* d_ws, size_t ws_size,
                              hipStream_t stream) {
    const float* x  = (const float*)d_in[0];
    const float* Wq = (const float*)d_in[1];
    const float* Wk = (const float*)d_in[2];
    const float* Wv = (const float*)d_in[3];
    const float* Wo = (const float*)d_in[4];
    const float* bo = (const float*)d_in[5];
    float* out = (float*)d_out;

    // Workspace layout (bytes). Opart overlays xh/WTq/WTk/WTv (disjoint
    // lifetimes: xh/WT die at qkv_gemm16 end; Opart born in attn_fwd).
    char* base = (char*)d_ws;
    f16*   Opart = (f16*)base;                   // 2*8*4096*64*2 = 8,388,608
    f16*   xh    = (f16*)base;                   // 5,242,880
    f16*   WTq   = xh + (size_t)NSEQ * DMODEL;
    f16*   WTk   = WTq + (size_t)INNER * DMODEL;
    f16*   WTv   = WTk + (size_t)INNER * DMODEL; // ends 7,208,960 < 8,388,608
    float* Ml    = (float*)(base + 8388608);     // 2*8*4096*2*4 = 524,288
    f16*   WoT   = (f16*)(base + 8912896);       // 655,360
    f16*   q16   = (f16*)(base + 9568256);       // 4,194,304
    f16*   k16   = q16 + (size_t)NHEAD * NSEQ * DHEAD;
    f16*   vT16  = k16 + (size_t)NHEAD * NSEQ * DHEAD;  // ends 22,151,168 B

    cvt_x<<<NSEQ * DMODEL / (256 * 8), 256, 0, stream>>>(x, xh);
    transpose_cvtW<<<dim3(10, 10, 4), 256, 0, stream>>>(
        Wq, Wk, Wv, Wo, WTq, WTk, WTv, WoT);

    qkv_gemm16<<<dim3(NHEAD, NSEQ / 128, 3), 256, 0, stream>>>(
        xh, WTq, WTk, WTv, q16, k16, vT16);
    attn_fwd<<<dim3(NSEQ / 128, NHEAD, KVSPLIT), 256, 0, stream>>>(
        q16, k16, vT16, Opart, Ml);
    out_gemm16<<<dim3(DMODEL / 64, NSEQ / 64), 256, 0, stream>>>(
        Opart, Ml, WoT, bo, out);
}

// Round 11
// 164.142 us; speedup vs baseline: 1.0815x; 1.0358x over previous
//
#include <hip/hip_runtime.h>
#include <math.h>

#define NSEQ   4096
#define DMODEL 640
#define NHEAD  8
#define DHEAD  64
#define INNER  512   // NHEAD*DHEAD
#define KVSPLIT 2

typedef _Float16 f16;
typedef _Float16 f16x8 __attribute__((ext_vector_type(8)));
typedef _Float16 f16x4 __attribute__((ext_vector_type(4)));
typedef float    f32x4 __attribute__((ext_vector_type(4)));

#define MFMA16(a, b, c) __builtin_amdgcn_mfma_f32_16x16x32_f16((a), (b), (c), 0, 0, 0)

// softmax scale 1/8 folded with log2(e): softmax runs in exp2 domain
#define QSCALE 0.18033688011112042f

// global -> LDS direct copy, 16B/lane, wave-uniform LDS base.
__device__ __forceinline__ void gl16(const f16* g, f16* l) {
    __builtin_amdgcn_global_load_lds(
        (const __attribute__((address_space(1))) unsigned int*)g,
        (__attribute__((address_space(3))) unsigned int*)l, 16, 0, 0);
}

// ---------------------------------------------------------------------------
// Prep: x (f32) -> xh (f16), 8 elems/thread
// ---------------------------------------------------------------------------
__global__ __launch_bounds__(256) void cvt_x(const float* __restrict__ x,
                                             f16* __restrict__ xh) {
    int i = (blockIdx.x * 256 + threadIdx.x) * 8;
    float4 a = *(const float4*)&x[i];
    float4 b = *(const float4*)&x[i + 4];
    f16x8 o = {(f16)a.x, (f16)a.y, (f16)a.z, (f16)a.w,
               (f16)b.x, (f16)b.y, (f16)b.z, (f16)b.w};
    *(f16x8*)&xh[i] = o;
}

// ---------------------------------------------------------------------------
// Prep: transpose+convert all four weights in ONE launch.
// z=0..2: Wq/Wk/Wv f32 [640][512] -> f16 [512][640]; z=3: Wo [512][640]->[640][512]
// ---------------------------------------------------------------------------
__global__ __launch_bounds__(256) void transpose_cvtW(
    const float* __restrict__ Wq, const float* __restrict__ Wk,
    const float* __restrict__ Wv, const float* __restrict__ Wo,
    f16* __restrict__ WTq, f16* __restrict__ WTk, f16* __restrict__ WTv,
    f16* __restrict__ WoT) {
    __shared__ __align__(16) f16 T[64][72];
    const int bz = blockIdx.z;
    const float* src = bz == 0 ? Wq : bz == 1 ? Wk : bz == 2 ? Wv : Wo;
    f16* dst = bz == 0 ? WTq : bz == 1 ? WTk : bz == 2 ? WTv : WoT;
    const int R = (bz < 3) ? DMODEL : INNER;   // src rows
    const int C = (bz < 3) ? INNER : DMODEL;   // src cols
    const int c0 = blockIdx.x * 64, r0 = blockIdx.y * 64;
    if (c0 >= C || r0 >= R) return;            // block-uniform early out
    const int t = threadIdx.x;
    {
        int r = t >> 2, cb = (t & 3) * 16;
#pragma unroll
        for (int i = 0; i < 16; i += 4) {
            float4 v = *(const float4*)&src[(size_t)(r0 + r) * C + c0 + cb + i];
            T[cb + i + 0][r] = (f16)v.x;
            T[cb + i + 1][r] = (f16)v.y;
            T[cb + i + 2][r] = (f16)v.z;
            T[cb + i + 3][r] = (f16)v.w;
        }
    }
    __syncthreads();
    {
        int c = t >> 2, rb = (t & 3) * 16;
        f16* d = dst + (size_t)(c0 + c) * R + r0 + rb;
        *(f16x8*)d = *(const f16x8*)&T[c][rb];
        *(f16x8*)(d + 8) = *(const f16x8*)&T[c][rb + 8];
    }
}

// ---------------------------------------------------------------------------
// QKV projection (round-10 form, unchanged): fragment-reuse M128xN64, K=64.
// Outputs: z=0 Q (prescaled) [h][n][d], z=1 K [h][n][d], z=2 V^T [h][d][n].
// ---------------------------------------------------------------------------
__global__ __launch_bounds__(256) void qkv_gemm16(
    const f16* __restrict__ xh,
    const f16* __restrict__ WTq, const f16* __restrict__ WTk,
    const f16* __restrict__ WTv,
    f16* __restrict__ q16, f16* __restrict__ k16, f16* __restrict__ vT16)
{
    __shared__ __align__(16) f16 S[12288];   // A: [0,8192) B: [8192,12288)
    f16* Xs = S;                              // [128 rows][64 cols]
    f16* Ws = S + 8192;                       // [64][64]

    const int bx = blockIdx.x;               // head / N-tile
    const int by = blockIdx.y;               // M-tile (128 rows)
    const int bz = blockIdx.z;               // 0=Q 1=K 2=V
    const f16* WT = (bz == 0) ? WTq : (bz == 1) ? WTk : WTv;

    const int tid = threadIdx.x;
    const int w = tid >> 6, lane = tid & 63;
    const int lr = lane & 15, lc = lane >> 4;
    const int srow8 = lane >> 3;
    const int le = 8 * ((lane & 7) ^ srow8);
    const int swz0 = 8 * (lc ^ (lr & 7));
    const int swz1 = 8 * ((lc + 4) ^ (lr & 7));
    const int m0 = by * 128, n0 = bx * 64;

    f32x4 acc[2][4] = {};

    for (int s = 0; s < DMODEL / 64; ++s) {
        const int k0 = s * 64;
#pragma unroll
        for (int c = 0; c < 4; ++c) {
            const int cc = 4 * w + c;
            gl16(xh + (size_t)(m0 + cc * 8 + srow8) * DMODEL + k0 + le,
                 &Xs[cc * 512]);
        }
#pragma unroll
        for (int c = 0; c < 2; ++c) {
            const int cc = 2 * w + c;
            gl16(WT + (size_t)(n0 + cc * 8 + srow8) * DMODEL + k0 + le,
                 &Ws[cc * 512]);
        }
        __syncthreads();
        f16x8 a0[2], a1[2];
#pragma unroll
        for (int g = 0; g < 2; ++g) {
            const int row = 32 * w + 16 * g + lr;
            a0[g] = *(const f16x8*)&Xs[row * 64 + swz0];
            a1[g] = *(const f16x8*)&Xs[row * 64 + swz1];
        }
#pragma unroll
        for (int nt = 0; nt < 4; ++nt) {
            f16x8 b0 = *(const f16x8*)&Ws[(nt * 16 + lr) * 64 + swz0];
            f16x8 b1 = *(const f16x8*)&Ws[(nt * 16 + lr) * 64 + swz1];
#pragma unroll
            for (int g = 0; g < 2; ++g)
                acc[g][nt] = MFMA16(a1[g], b1, MFMA16(a0[g], b0, acc[g][nt]));
        }
        __syncthreads();
    }

    const float sc = (bz == 0) ? QSCALE : 1.0f;
    if (bz < 2) {
#pragma unroll
        for (int g = 0; g < 2; ++g)
#pragma unroll
            for (int nt = 0; nt < 4; ++nt)
#pragma unroll
                for (int r = 0; r < 4; ++r)
                    S[(32 * w + 16 * g + 4 * lc + r) * 72 + nt * 16 + lr] =
                        (f16)(acc[g][nt][r] * sc);
        __syncthreads();
        f16* ob = ((bz == 0) ? q16 : k16) + (size_t)bx * NSEQ * DHEAD;
#pragma unroll
        for (int p = 0; p < 2; ++p) {
            const int rr = p * 64 + (tid >> 2), cb = (tid & 3) * 16;
            f16* dst = ob + (size_t)(m0 + rr) * DHEAD + cb;
            *(f16x8*)dst = *(const f16x8*)&S[rr * 72 + cb];
            *(f16x8*)(dst + 8) = *(const f16x8*)&S[rr * 72 + cb + 8];
        }
    } else {
#pragma unroll
        for (int g = 0; g < 2; ++g)
#pragma unroll
            for (int nt = 0; nt < 4; ++nt)
#pragma unroll
                for (int r = 0; r < 4; ++r)
                    S[(nt * 16 + lr) * 136 + 32 * w + 16 * g + 4 * lc + r] =
                        (f16)acc[g][nt][r];
        __syncthreads();
        const int rr = tid >> 2, cb = (tid & 3) * 32;
        f16* dst = vT16 + ((size_t)bx * DHEAD + rr) * NSEQ + m0 + cb;
        *(f16x8*)dst        = *(const f16x8*)&S[rr * 136 + cb];
        *(f16x8*)(dst + 8)  = *(const f16x8*)&S[rr * 136 + cb + 8];
        *(f16x8*)(dst + 16) = *(const f16x8*)&S[rr * 136 + cb + 16];
        *(f16x8*)(dst + 24) = *(const f16x8*)&S[rr * 136 + cb + 24];
    }
}

// ---------------------------------------------------------------------------
// Flash attention with T15 DOUBLE-PIPELINE: iteration j runs QK^T(j) [MFMA]
// then finish(j-1) = softmax+P+PV [VALU/TRANS then MFMA] — softmax of the
// previous tile overlaps the current tile's QK^T in the same wave. S kept in
// two named register buffers (sA/sB, static indexing); K 2-deep, V 4-DEEP
// (PV(j-1) reads V[j-1] while prefetch writes V[j+1] -> distance 2), loop
// unrolled x4 so all buffer indices are compile-time. One barrier/iter.
// Numerics identical to round 10 (same tile order/arithmetic).
// ---------------------------------------------------------------------------
__global__ __launch_bounds__(256, 2) void attn_fwd(
    const f16* __restrict__ q16, const f16* __restrict__ k16,
    const f16* __restrict__ vT16, f16* __restrict__ Opart,
    float* __restrict__ Ml)
{
    __shared__ __align__(16) f16 KsB[2][4096];   // [kv 64][d 64] swizzled
    __shared__ __align__(16) f16 VtB[4][4096];   // [d 64][kv 64] swizzled
    __shared__ __align__(16) f16 Ps[8192];       // [q 128][kv 64] swizzled

    const int lin = blockIdx.x + 32 * blockIdx.y + 256 * blockIdx.z;
    const int h  = lin & 7;
    const int qb = (lin >> 3) & 31;              // q-tile of 128 rows
    const int sp = lin >> 8;                     // kv half 0/1

    const int tid = threadIdx.x;
    const int w = tid >> 6, lane = tid & 63;
    const int lr = lane & 15, lc = lane >> 4;
    const int srow8 = lane >> 3;
    const int le = 8 * ((lane & 7) ^ srow8);
    const int swz0 = 8 * (lc ^ (lr & 7));
    const int swz1 = 8 * ((lc + 4) ^ (lr & 7));

    const f16* kp = k16 + ((size_t)h * NSEQ + sp * (NSEQ / KVSPLIT)) * DHEAD;
    const f16* vp = vT16 + (size_t)h * DHEAD * NSEQ + sp * (NSEQ / KVSPLIT);

    // Q fragments: wave rows qb*128 + 32w + 16g + lr, g=0,1 (prescaled)
    f16x8 qf[2][2];
#pragma unroll
    for (int g = 0; g < 2; ++g) {
        const f16* qp = q16 +
            ((size_t)h * NSEQ + qb * 128 + 32 * w + 16 * g + lr) * DHEAD;
        qf[g][0] = *(const f16x8*)&qp[lc * 8];
        qf[g][1] = *(const f16x8*)&qp[32 + lc * 8];
    }

    float m_run[2] = {-INFINITY, -INFINITY}, l_run[2] = {0.f, 0.f};
    f32x4 o[2][4] = {};
    f32x4 sA[2][4], sB[2][4];
    const int NT = NSEQ / KVSPLIT / 64;          // 32

#define PREFETCH(J, KB, VB) {                                                 \
    _Pragma("unroll")                                                         \
    for (int c = 0; c < 2; ++c) {                                             \
        const int cc = 2 * w + c;                                             \
        gl16(kp + (size_t)((J) * 64 + cc * 8 + srow8) * DHEAD + le,           \
             &KsB[KB][cc * 512]);                                             \
        gl16(vp + (size_t)(cc * 8 + srow8) * NSEQ + (J) * 64 + le,            \
             &VtB[VB][cc * 512]);                                             \
    } }

#define QKT(KB, S) {                                                          \
    const f32x4 z4 = {0.f, 0.f, 0.f, 0.f};                                    \
    _Pragma("unroll")                                                         \
    for (int t = 0; t < 4; ++t) {                                             \
        f16x8 ka = *(const f16x8*)&KsB[KB][(t * 16 + lr) * 64 + swz0];        \
        f16x8 kb = *(const f16x8*)&KsB[KB][(t * 16 + lr) * 64 + swz1];        \
        _Pragma("unroll")                                                     \
        for (int g = 0; g < 2; ++g)                                           \
            S[g][t] = MFMA16(kb, qf[g][1], MFMA16(ka, qf[g][0], z4));         \
    } }

#define FINISH(VB, S) {                                                       \
    float pm[2];                                                              \
    _Pragma("unroll")                                                         \
    for (int g = 0; g < 2; ++g) {                                             \
        float mm = S[g][0][0];                                                \
        _Pragma("unroll")                                                     \
        for (int t = 0; t < 4; ++t)                                           \
            _Pragma("unroll")                                                 \
            for (int r = 0; r < 4; ++r) mm = fmaxf(mm, S[g][t][r]);           \
        mm = fmaxf(mm, __shfl_xor(mm, 16));                                   \
        mm = fmaxf(mm, __shfl_xor(mm, 32));                                   \
        pm[g] = mm;                                                           \
    }                                                                         \
    if (__any((pm[0] > m_run[0]) | (pm[1] > m_run[1]))) {                     \
        _Pragma("unroll")                                                     \
        for (int g = 0; g < 2; ++g) {                                         \
            const float mn = fmaxf(m_run[g], pm[g]);                          \
            const float al = __builtin_amdgcn_exp2f(m_run[g] - mn);           \
            m_run[g] = mn;                                                    \
            l_run[g] *= al;                                                   \
            _Pragma("unroll")                                                 \
            for (int dt = 0; dt < 4; ++dt) o[g][dt] *= al;                    \
        }                                                                     \
    }                                                                         \
    _Pragma("unroll")                                                         \
    for (int g = 0; g < 2; ++g) {                                             \
        float ps = 0.f;                                                       \
        _Pragma("unroll")                                                     \
        for (int t = 0; t < 4; ++t)                                           \
            _Pragma("unroll")                                                 \
            for (int r = 0; r < 4; ++r) {                                     \
                S[g][t][r] = __builtin_amdgcn_exp2f(S[g][t][r] - m_run[g]);   \
                ps += S[g][t][r];                                             \
            }                                                                 \
        ps += __shfl_xor(ps, 16);                                             \
        ps += __shfl_xor(ps, 32);                                             \
        l_run[g] += ps;                                                       \
    }                                                                         \
    _Pragma("unroll")                                                         \
    for (int g = 0; g < 2; ++g) {                                             \
        const int row = 32 * w + 16 * g + lr;                                 \
        _Pragma("unroll")                                                     \
        for (int t = 0; t < 4; ++t) {                                         \
            f16x4 pk = {(f16)S[g][t][0], (f16)S[g][t][1],                     \
                        (f16)S[g][t][2], (f16)S[g][t][3]};                    \
            const int col = (16 * t + 4 * lc) ^ ((lr & 7) << 3);              \
            *(f16x4*)&Ps[row * 64 + col] = pk;                                \
        }                                                                     \
    }                                                                         \
    {                                                                         \
        f16x8 pb[2][2];                                                       \
        _Pragma("unroll")                                                     \
        for (int g = 0; g < 2; ++g) {                                         \
            const int row = 32 * w + 16 * g + lr;                             \
            pb[g][0] = *(const f16x8*)&Ps[row * 64 + swz0];                   \
            pb[g][1] = *(const f16x8*)&Ps[row * 64 + swz1];                   \
        }                                                                     \
        _Pragma("unroll")                                                     \
        for (int dt = 0; dt < 4; ++dt) {                                      \
            f16x8 va0 = *(const f16x8*)&VtB[VB][(dt * 16 + lr) * 64 + swz0];  \
            f16x8 va1 = *(const f16x8*)&VtB[VB][(dt * 16 + lr) * 64 + swz1];  \
            _Pragma("unroll")                                                 \
            for (int g = 0; g < 2; ++g)                                       \
                o[g][dt] = MFMA16(va1, pb[g][1],                              \
                                  MFMA16(va0, pb[g][0], o[g][dt]));           \
        }                                                                     \
    } }

// BODY(j, u=j&3): prefetch(j+1) | QK^T(j)->SCUR | finish(j-1) on SPRV | bar.
// K buf j&1 = u&1; V bufs: write (u+1)&3, read (u+3)&3 — all compile-time.
#define BODY(J, U, SCUR, SPRV) {                                              \
    if ((J) + 1 < NT) PREFETCH((J) + 1, ((U) + 1) & 1, ((U) + 1) & 3);        \
    QKT((U) & 1, SCUR);                                                       \
    if ((J) > 0) FINISH(((U) + 3) & 3, SPRV);                                 \
    __syncthreads();                                                          \
    }

    // prologue: stage tile 0 into K0/V0
    PREFETCH(0, 0, 0);
    __syncthreads();

    BODY(0, 0, sA, sB);
    BODY(1, 1, sB, sA);
    BODY(2, 2, sA, sB);
    BODY(3, 3, sB, sA);
    for (int m = 1; m < 8; ++m) {
        const int j = 4 * m;
        BODY(j, 0, sA, sB);
        BODY(j + 1, 1, sB, sA);
        BODY(j + 2, 2, sA, sB);
        BODY(j + 3, 3, sB, sA);
    }
    FINISH(3, sB);                               // tile 31: V[31&3], s = sB

#undef BODY
#undef FINISH
#undef QKT
#undef PREFETCH

    // ---- epilogue: per-split normalized O (f16) + (m,l)
#pragma unroll
    for (int g = 0; g < 2; ++g) {
        const float linv = 1.0f / l_run[g];
        const size_t qg = (size_t)qb * 128 + 32 * w + 16 * g + lr;
        f16* ob = Opart + (((size_t)(sp * 8 + h)) * NSEQ + qg) * DHEAD;
#pragma unroll
        for (int dt = 0; dt < 4; ++dt) {
            f16x4 ov = {(f16)(o[g][dt][0] * linv), (f16)(o[g][dt][1] * linv),
                        (f16)(o[g][dt][2] * linv), (f16)(o[g][dt][3] * linv)};
            *(f16x4*)&ob[dt * 16 + 4 * lc] = ov;
        }
        if (lc == 0) {
            float2 ml = make_float2(m_run[g], l_run[g]);
            *(float2*)&Ml[(((size_t)(sp * 8 + h)) * NSEQ + qg) * 2] = ml;
        }
    }
}

// ---------------------------------------------------------------------------
// Output projection + 2-way kv-split combine (round-10 form, unchanged).
// K-step s8 == head.
// ---------------------------------------------------------------------------
__global__ __launch_bounds__(256) void out_gemm16(
    const f16* __restrict__ Opart, const float* __restrict__ Ml,
    const f16* __restrict__ WoT,
    const float* __restrict__ bias, float* __restrict__ C)
{
    __shared__ __align__(16) f16 Xs[4096];
    __shared__ __align__(16) f16 Ws[4096];

    const int bx = blockIdx.x;   // N-tile 0..9
    const int by = blockIdx.y;   // M-tile 0..63
    const int tid = threadIdx.x;
    const int w = tid >> 6, lane = tid & 63;
    const int lr = lane & 15, lc = lane >> 4;
    const int srow8 = lane >> 3;
    const int j = lane & 7;
    const int le = 8 * (j ^ srow8);
    const int swz0 = 8 * (lc ^ (lr & 7));
    const int swz1 = 8 * ((lc + 4) ^ (lr & 7));
    const int m0 = by * 64, n0 = bx * 64;

    f32x4 acc[4] = {};

    for (int s8 = 0; s8 < 8; ++s8) {         // K-step == head
        const int k0 = s8 * 64;
#pragma unroll
        for (int c = 0; c < 2; ++c) {
            const int cc = w * 2 + c;
            gl16(WoT + (size_t)(n0 + cc * 8 + srow8) * INNER + k0 + le,
                 &Ws[cc * 512]);
            const int row = cc * 8 + srow8;
            const size_t q = (size_t)m0 + row;
            f16x8 o0 = *(const f16x8*)&Opart[((size_t)s8 * NSEQ + q) * DHEAD + 8 * j];
            f16x8 o1 = *(const f16x8*)&Opart[((size_t)(8 + s8) * NSEQ + q) * DHEAD + 8 * j];
            float2 ml0 = *(const float2*)&Ml[((size_t)s8 * NSEQ + q) * 2];
            float2 ml1 = *(const float2*)&Ml[((size_t)(8 + s8) * NSEQ + q) * 2];
            const float mx = fmaxf(ml0.x, ml1.x);
            float w0 = ml0.y * __builtin_amdgcn_exp2f(ml0.x - mx);
            float w1 = ml1.y * __builtin_amdgcn_exp2f(ml1.x - mx);
            const float inv = 1.0f / (w0 + w1);
            w0 *= inv; w1 *= inv;
            f16x8 a8;
#pragma unroll
            for (int e = 0; e < 8; ++e)
                a8[e] = (f16)((float)o0[e] * w0 + (float)o1[e] * w1);
            *(f16x8*)&Xs[row * 64 + 8 * (j ^ (row & 7))] = a8;
        }
        __syncthreads();
        f16x8 a0 = *(const f16x8*)&Xs[(16 * w + lr) * 64 + swz0];
        f16x8 a1 = *(const f16x8*)&Xs[(16 * w + lr) * 64 + swz1];
#pragma unroll
        for (int nt = 0; nt < 4; ++nt) {
            f16x8 b0 = *(const f16x8*)&Ws[(nt * 16 + lr) * 64 + swz0];
            f16x8 b1 = *(const f16x8*)&Ws[(nt * 16 + lr) * 64 + swz1];
            acc[nt] = MFMA16(a1, b1, MFMA16(a0, b0, acc[nt]));
        }
        __syncthreads();
    }

#pragma unroll
    for (int nt = 0; nt < 4; ++nt) {
        const float b = bias[n0 + nt * 16 + lr];
#pragma unroll
        for (int r = 0; r < 4; ++r)
            C[(size_t)(m0 + 16 * w + lc * 4 + r) * DMODEL + n0 + nt * 16 + lr] =
                acc[nt][r] + b;
    }
}

extern "C" void kernel_launch(void* const* d_in, const int* in_sizes, int n_in,
                              void* d_out, int out_size, void* d_ws, size_t ws_size,
                              hipStream_t stream) {
    const float* x  = (const float*)d_in[0];
    const float* Wq = (const float*)d_in[1];
    const float* Wk = (const float*)d_in[2];
    const float* Wv = (const float*)d_in[3];
    const float* Wo = (const float*)d_in[4];
    const float* bo = (const float*)d_in[5];
    float* out = (float*)d_out;

    // Workspace layout (bytes). Opart overlays xh/WTq/WTk/WTv (disjoint
    // lifetimes: xh/WT die at qkv_gemm16 end; Opart born in attn_fwd).
    char* base = (char*)d_ws;
    f16*   Opart = (f16*)base;                   // 2*8*4096*64*2 = 8,388,608
    f16*   xh    = (f16*)base;                   // 5,242,880
    f16*   WTq   = xh + (size_t)NSEQ * DMODEL;
    f16*   WTk   = WTq + (size_t)INNER * DMODEL;
    f16*   WTv   = WTk + (size_t)INNER * DMODEL; // ends 7,208,960 < 8,388,608
    float* Ml    = (float*)(base + 8388608);     // 2*8*4096*2*4 = 524,288
    f16*   WoT   = (f16*)(base + 8912896);       // 655,360
    f16*   q16   = (f16*)(base + 9568256);       // 4,194,304
    f16*   k16   = q16 + (size_t)NHEAD * NSEQ * DHEAD;
    f16*   vT16  = k16 + (size_t)NHEAD * NSEQ * DHEAD;  // ends 22,151,168 B

    cvt_x<<<NSEQ * DMODEL / (256 * 8), 256, 0, stream>>>(x, xh);
    transpose_cvtW<<<dim3(10, 10, 4), 256, 0, stream>>>(
        Wq, Wk, Wv, Wo, WTq, WTk, WTv, WoT);

    qkv_gemm16<<<dim3(NHEAD, NSEQ / 128, 3), 256, 0, stream>>>(
        xh, WTq, WTk, WTv, q16, k16, vT16);
    attn_fwd<<<dim3(NSEQ / 128, NHEAD, KVSPLIT), 256, 0, stream>>>(
        q16, k16, vT16, Opart, Ml);
    out_gemm16<<<dim3(DMODEL / 64, NSEQ / 64), 256, 0, stream>>>(
        Opart, Ml, WoT, bo, out);
}